// Round 1
// baseline (1019.357 us; speedup 1.0000x reference)
//
#include <hip/hip_runtime.h>

// Output layout in d_out (all float32):
//   [0        , M)        rows   (out_idx[0]),  M = B*n*n
//   [M        , 2M)       cols   (out_idx[1])
//   [2M       , 2M + M*D) vals   (out_val, row-major [M, D])
//
// rows[q] = q / n          (== gid*n + i)
// cols[q] = (q/n^2)*n + q%n (== gid*n + j)

__global__ void fill_idx_kernel(float* __restrict__ rows,
                                float* __restrict__ cols,
                                int M, int n, int n2) {
    int q0 = (blockIdx.x * blockDim.x + threadIdx.x) * 4;
    if (q0 >= M) return;
    float4 rv, cv;
    {
        int q = q0;
        rv.x = (float)(q / n);
        cv.x = (float)((q / n2) * n + (q % n));
        q = q0 + 1;
        rv.y = (float)(q / n);
        cv.y = (float)((q / n2) * n + (q % n));
        q = q0 + 2;
        rv.z = (float)(q / n);
        cv.z = (float)((q / n2) * n + (q % n));
        q = q0 + 3;
        rv.w = (float)(q / n);
        cv.w = (float)((q / n2) * n + (q % n));
    }
    *(float4*)(rows + q0) = rv;
    *(float4*)(cols + q0) = cv;
}

// One thread per (edge, float4 chunk). D assumed divisible by 4 (D=64 here).
// chunksPerEdge = D/4 = 16 lanes handle one edge: coalesced float4 reads of
// edge_attr, 256B-contiguous destination row, 4 scalar atomicAdds per lane
// (duplicate (g,src,dst) triples exist, so atomics are required).
__global__ void scatter_add_kernel(const int* __restrict__ ei,
                                   const float* __restrict__ ea,
                                   const int* __restrict__ batch,
                                   float* __restrict__ vals,
                                   int E, int D, int n, int n2) {
    int chunksPerEdge = D >> 2;
    long long tid = (long long)blockIdx.x * blockDim.x + threadIdx.x;
    int e = (int)(tid / chunksPerEdge);
    int ch = (int)(tid % chunksPerEdge);
    if (e >= E) return;

    int r = ei[e];
    int c = ei[E + e];
    int g = batch[r];
    long long pos = (long long)g * n2 + (long long)(r - g * n) * n + (long long)(c - g * n);

    float4 src = *(const float4*)(ea + (long long)e * D + ch * 4);
    float* dst = vals + pos * D + ch * 4;
    atomicAdd(dst + 0, src.x);
    atomicAdd(dst + 1, src.y);
    atomicAdd(dst + 2, src.z);
    atomicAdd(dst + 3, src.w);
}

extern "C" void kernel_launch(void* const* d_in, const int* in_sizes, int n_in,
                              void* d_out, int out_size, void* d_ws, size_t ws_size,
                              hipStream_t stream) {
    const int* edge_index = (const int*)d_in[0];   // [2, E]
    const float* edge_attr = (const float*)d_in[1]; // [E, D]
    const int* batch = (const int*)d_in[2];         // [B*n]

    const int E  = in_sizes[0] / 2;
    const int D  = in_sizes[1] / E;
    const int M  = out_size / (D + 2);   // B*n*n
    const int BN = in_sizes[2];          // B*n
    const int n  = M / BN;
    const int n2 = n * n;

    float* rows = (float*)d_out;
    float* cols = rows + M;
    float* vals = cols + M;

    // Zero the value region (out_val starts as zeros; padded slots stay zero).
    hipMemsetAsync(vals, 0, (size_t)M * D * sizeof(float), stream);

    // Fill the full adjacency index list (closed form).
    {
        int threads = (M + 3) / 4;
        int block = 256;
        int grid = (threads + block - 1) / block;
        fill_idx_kernel<<<grid, block, 0, stream>>>(rows, cols, M, n, n2);
    }

    // Scatter-add original edge attributes.
    {
        long long total = (long long)E * (D / 4);
        int block = 256;
        long long grid = (total + block - 1) / block;
        scatter_add_kernel<<<(int)grid, block, 0, stream>>>(
            edge_index, edge_attr, batch, vals, E, D, n, n2);
    }
}

// Round 3
// 734.379 us; speedup vs baseline: 1.3881x; 1.3881x over previous
//
#include <hip/hip_runtime.h>

// Output layout in d_out (all float32):
//   [0, M)          rows (out_idx[0]),  M = B*n*n
//   [M, 2M)         cols (out_idx[1])
//   [2M, 2M + M*D)  vals (out_val, row-major [M, D])
//
// Strategy: build per-slot edge chains (head[M], next[E] in ws) with one
// atomicExch per edge (head array is 8.4MB -> L2-resident, cheap), then a
// single fused pass writes the ENTIRE output (indices + values) with
// nontemporal stores: empty slots get zeros (replacing the 536MB memset),
// occupied slots get the chain-walked sum (no value atomics at all).

typedef float vfloat4 __attribute__((ext_vector_type(4)));

__global__ void build_chain_kernel(const int* __restrict__ ei,
                                   const int* __restrict__ batch,
                                   int* __restrict__ head,
                                   int* __restrict__ next,
                                   int E, int n, int n2) {
    int e = blockIdx.x * blockDim.x + threadIdx.x;
    if (e >= E) return;
    int r = ei[e];
    int c = ei[E + e];
    int g = batch[r];
    int pos = g * n2 + (r - g * n) * n + (c - g * n);
    next[e] = atomicExch(&head[pos], e);
}

// 16 lanes (D/4) per output row; rows consecutive -> wave covers 1KB of vals
// contiguously. Chain is usually empty (zero row) or length-1 (one gathered
// 256B edge_attr row, coalesced across the 16 lanes).
__global__ void fused_output_kernel(const float* __restrict__ ea,
                                    const int* __restrict__ head,
                                    const int* __restrict__ next,
                                    float* __restrict__ rows,
                                    float* __restrict__ cols,
                                    float* __restrict__ vals,
                                    int M, int D, int n, int n2) {
    unsigned chunks = (unsigned)(D >> 2);
    unsigned tid = blockIdx.x * blockDim.x + threadIdx.x;
    unsigned q = tid / chunks;
    unsigned ch = tid - q * chunks;
    if (q >= (unsigned)M) return;

    vfloat4 acc = {0.f, 0.f, 0.f, 0.f};
    int e = head[q];
    while (e >= 0) {
        const vfloat4 v = *(const vfloat4*)(ea + (size_t)e * D + ch * 4);
        acc += v;
        e = next[e];
    }
    __builtin_nontemporal_store(acc, (vfloat4*)(vals + (size_t)q * D + ch * 4));

    if (ch == 0) {
        unsigned rr = q / (unsigned)n;
        unsigned gg = q / (unsigned)n2;
        unsigned cc = gg * (unsigned)n + (q - rr * (unsigned)n);
        __builtin_nontemporal_store((float)rr, rows + q);
        __builtin_nontemporal_store((float)cc, cols + q);
    }
}

// ---------- fallback (round-1 verified path) if ws is too small ----------
__global__ void fill_idx_kernel(float* __restrict__ rows,
                                float* __restrict__ cols,
                                int M, int n, int n2) {
    int q0 = (blockIdx.x * blockDim.x + threadIdx.x) * 4;
    if (q0 >= M) return;
    float4 rv, cv;
    int q = q0;
    rv.x = (float)(q / n); cv.x = (float)((q / n2) * n + (q % n)); q++;
    rv.y = (float)(q / n); cv.y = (float)((q / n2) * n + (q % n)); q++;
    rv.z = (float)(q / n); cv.z = (float)((q / n2) * n + (q % n)); q++;
    rv.w = (float)(q / n); cv.w = (float)((q / n2) * n + (q % n));
    *(float4*)(rows + q0) = rv;
    *(float4*)(cols + q0) = cv;
}

__global__ void scatter_add_kernel(const int* __restrict__ ei,
                                   const float* __restrict__ ea,
                                   const int* __restrict__ batch,
                                   float* __restrict__ vals,
                                   int E, int D, int n, int n2) {
    int chunksPerEdge = D >> 2;
    long long tid = (long long)blockIdx.x * blockDim.x + threadIdx.x;
    int e = (int)(tid / chunksPerEdge);
    int ch = (int)(tid % chunksPerEdge);
    if (e >= E) return;
    int r = ei[e];
    int c = ei[E + e];
    int g = batch[r];
    long long pos = (long long)g * n2 + (long long)(r - g * n) * n + (long long)(c - g * n);
    float4 src = *(const float4*)(ea + (long long)e * D + ch * 4);
    float* dst = vals + pos * D + ch * 4;
    atomicAdd(dst + 0, src.x);
    atomicAdd(dst + 1, src.y);
    atomicAdd(dst + 2, src.z);
    atomicAdd(dst + 3, src.w);
}
// -------------------------------------------------------------------------

extern "C" void kernel_launch(void* const* d_in, const int* in_sizes, int n_in,
                              void* d_out, int out_size, void* d_ws, size_t ws_size,
                              hipStream_t stream) {
    const int* edge_index = (const int*)d_in[0];    // [2, E]
    const float* edge_attr = (const float*)d_in[1]; // [E, D]
    const int* batch = (const int*)d_in[2];         // [B*n]

    const int E  = in_sizes[0] / 2;
    const int D  = in_sizes[1] / E;
    const int M  = out_size / (D + 2);   // B*n*n
    const int BN = in_sizes[2];          // B*n
    const int n  = M / BN;
    const int n2 = n * n;

    float* rows = (float*)d_out;
    float* cols = rows + M;
    float* vals = cols + M;

    const size_t ws_need = ((size_t)M + (size_t)E) * sizeof(int);
    if (ws_size >= ws_need) {
        int* head = (int*)d_ws;      // [M]
        int* next = head + M;        // [E]

        // head = -1 everywhere (0xFF bytes)
        (void)hipMemsetAsync(head, 0xFF, (size_t)M * sizeof(int), stream);

        {
            int block = 256;
            int grid = (E + block - 1) / block;
            build_chain_kernel<<<grid, block, 0, stream>>>(
                edge_index, batch, head, next, E, n, n2);
        }
        {
            long long total = (long long)M * (D / 4);
            int block = 256;
            long long grid = (total + block - 1) / block;
            fused_output_kernel<<<(int)grid, block, 0, stream>>>(
                edge_attr, head, next, rows, cols, vals, M, D, n, n2);
        }
    } else {
        // Fallback: round-1 verified path.
        (void)hipMemsetAsync(vals, 0, (size_t)M * D * sizeof(float), stream);
        {
            int threads = (M + 3) / 4;
            int block = 256;
            int grid = (threads + block - 1) / block;
            fill_idx_kernel<<<grid, block, 0, stream>>>(rows, cols, M, n, n2);
        }
        {
            long long total = (long long)E * (D / 4);
            int block = 256;
            long long grid = (total + block - 1) / block;
            scatter_add_kernel<<<(int)grid, block, 0, stream>>>(
                edge_index, edge_attr, batch, vals, E, D, n, n2);
        }
    }
}

// Round 4
// 733.162 us; speedup vs baseline: 1.3904x; 1.0017x over previous
//
#include <hip/hip_runtime.h>

// Output layout in d_out (all float32):
//   [0, M)          rows (out_idx[0]),  M = B*n*n
//   [M, 2M)         cols (out_idx[1])
//   [2M, 2M + M*D)  vals (out_val, row-major [M, D])
//
// Strategy (round 4): decouple streaming fill from latency-bound gather.
//   1. memset vals to 0 (rocclr fill hits ~6.3 TB/s).
//   2. build per-slot edge chains (head[M], next[E] in ws) with one
//      atomicExch per edge (head is 8.4MB -> LLC-resident, cheap).
//   3. gather pass: early-exit on empty slots (79%); occupied slots walk the
//      chain and overwrite the zero row with the sum (single writer, no
//      atomics; stream order guarantees the fill completed).
//   4. closed-form index fill for rows/cols.

typedef float vfloat4 __attribute__((ext_vector_type(4)));

__global__ void build_chain_kernel(const int* __restrict__ ei,
                                   const int* __restrict__ batch,
                                   int* __restrict__ head,
                                   int* __restrict__ next,
                                   int E, int n, int n2) {
    int e = blockIdx.x * blockDim.x + threadIdx.x;
    if (e >= E) return;
    int r = ei[e];
    int c = ei[E + e];
    int g = batch[r];
    int pos = g * n2 + (r - g * n) * n + (c - g * n);
    next[e] = atomicExch(&head[pos], e);
}

// CHUNKS lanes (D/4) per output row. Empty slots (head<0) exit after one
// coalesced 4B head read. Occupied slots gather the chain (256B coalesced
// reads of ea across the CHUNKS lanes) and overwrite the zeroed row.
template <int CHUNKS>
__global__ void gather_occupied_kernel(const float* __restrict__ ea,
                                       const int* __restrict__ head,
                                       const int* __restrict__ next,
                                       float* __restrict__ vals,
                                       int M, int D) {
    unsigned tid = blockIdx.x * blockDim.x + threadIdx.x;
    unsigned q, ch;
    if (CHUNKS > 0) {
        q = tid / (unsigned)CHUNKS;       // constexpr -> shift
        ch = tid & (unsigned)(CHUNKS - 1);
    } else {
        unsigned chunks = (unsigned)(D >> 2);
        q = tid / chunks;
        ch = tid - q * chunks;
    }
    if (q >= (unsigned)M) return;

    int e = head[q];
    if (e < 0) return;  // 79% of slots: zeros already in place from memset

    vfloat4 acc = {0.f, 0.f, 0.f, 0.f};
    do {
        const vfloat4 v = *(const vfloat4*)(ea + (size_t)e * D + ch * 4);
        acc += v;
        e = next[e];
    } while (e >= 0);
    __builtin_nontemporal_store(acc, (vfloat4*)(vals + (size_t)q * D + ch * 4));
}

__global__ void fill_idx_kernel(float* __restrict__ rows,
                                float* __restrict__ cols,
                                int M, int n, int n2) {
    int q0 = (blockIdx.x * blockDim.x + threadIdx.x) * 4;
    if (q0 >= M) return;
    float4 rv, cv;
    int q = q0;
    rv.x = (float)(q / n); cv.x = (float)((q / n2) * n + (q % n)); q++;
    rv.y = (float)(q / n); cv.y = (float)((q / n2) * n + (q % n)); q++;
    rv.z = (float)(q / n); cv.z = (float)((q / n2) * n + (q % n)); q++;
    rv.w = (float)(q / n); cv.w = (float)((q / n2) * n + (q % n));
    *(float4*)(rows + q0) = rv;
    *(float4*)(cols + q0) = cv;
}

// ---------- fallback (round-1 verified path) if ws is too small ----------
__global__ void scatter_add_kernel(const int* __restrict__ ei,
                                   const float* __restrict__ ea,
                                   const int* __restrict__ batch,
                                   float* __restrict__ vals,
                                   int E, int D, int n, int n2) {
    int chunksPerEdge = D >> 2;
    long long tid = (long long)blockIdx.x * blockDim.x + threadIdx.x;
    int e = (int)(tid / chunksPerEdge);
    int ch = (int)(tid % chunksPerEdge);
    if (e >= E) return;
    int r = ei[e];
    int c = ei[E + e];
    int g = batch[r];
    long long pos = (long long)g * n2 + (long long)(r - g * n) * n + (long long)(c - g * n);
    float4 src = *(const float4*)(ea + (long long)e * D + ch * 4);
    float* dst = vals + pos * D + ch * 4;
    atomicAdd(dst + 0, src.x);
    atomicAdd(dst + 1, src.y);
    atomicAdd(dst + 2, src.z);
    atomicAdd(dst + 3, src.w);
}
// -------------------------------------------------------------------------

extern "C" void kernel_launch(void* const* d_in, const int* in_sizes, int n_in,
                              void* d_out, int out_size, void* d_ws, size_t ws_size,
                              hipStream_t stream) {
    const int* edge_index = (const int*)d_in[0];    // [2, E]
    const float* edge_attr = (const float*)d_in[1]; // [E, D]
    const int* batch = (const int*)d_in[2];         // [B*n]

    const int E  = in_sizes[0] / 2;
    const int D  = in_sizes[1] / E;
    const int M  = out_size / (D + 2);   // B*n*n
    const int BN = in_sizes[2];          // B*n
    const int n  = M / BN;
    const int n2 = n * n;

    float* rows = (float*)d_out;
    float* cols = rows + M;
    float* vals = cols + M;

    const size_t ws_need = ((size_t)M + (size_t)E) * sizeof(int);
    if (ws_size >= ws_need && (D & 3) == 0) {
        int* head = (int*)d_ws;      // [M]
        int* next = head + M;        // [E]

        // 1. zero the value region (streaming fill at ~6.3 TB/s)
        (void)hipMemsetAsync(vals, 0, (size_t)M * D * sizeof(float), stream);
        // 2. head = -1 everywhere
        (void)hipMemsetAsync(head, 0xFF, (size_t)M * sizeof(int), stream);

        {
            int block = 256;
            int grid = (E + block - 1) / block;
            build_chain_kernel<<<grid, block, 0, stream>>>(
                edge_index, batch, head, next, E, n, n2);
        }
        {
            long long total = (long long)M * (D / 4);
            int block = 256;
            long long grid = (total + block - 1) / block;
            if (D == 64) {
                gather_occupied_kernel<16><<<(int)grid, block, 0, stream>>>(
                    edge_attr, head, next, vals, M, D);
            } else {
                gather_occupied_kernel<0><<<(int)grid, block, 0, stream>>>(
                    edge_attr, head, next, vals, M, D);
            }
        }
        {
            int threads = (M + 3) / 4;
            int block = 256;
            int grid = (threads + block - 1) / block;
            fill_idx_kernel<<<grid, block, 0, stream>>>(rows, cols, M, n, n2);
        }
    } else {
        // Fallback: round-1 verified path.
        (void)hipMemsetAsync(vals, 0, (size_t)M * D * sizeof(float), stream);
        {
            int threads = (M + 3) / 4;
            int block = 256;
            int grid = (threads + block - 1) / block;
            fill_idx_kernel<<<grid, block, 0, stream>>>(rows, cols, M, n, n2);
        }
        {
            long long total = (long long)E * (D / 4);
            int block = 256;
            long long grid = (total + block - 1) / block;
            scatter_add_kernel<<<(int)grid, block, 0, stream>>>(
                edge_index, edge_attr, batch, vals, E, D, n, n2);
        }
    }
}